// Round 6
// baseline (221.494 us; speedup 1.0000x reference)
//
#include <hip/hip_runtime.h>
#include <hip/hip_fp16.h>

typedef __attribute__((ext_vector_type(8))) short short8;
typedef __attribute__((ext_vector_type(4))) float f32x4;
typedef unsigned short ushort_t;
typedef unsigned int uint_t;

#define B_SZ 32
#define T_SZ 4096
#define D_IN 256
#define H_SZ 256
#define M_SZ (B_SZ * T_SZ)  // 131072
#define CHUNK 64
#define NCHUNK (T_SZ / CHUNK)  // 64

__device__ __forceinline__ ushort_t f2bf(float f) {
  unsigned int u = __float_as_uint(f);
  unsigned int r = (u + 0x7FFFu + ((u >> 16) & 1u)) >> 16;
  return (ushort_t)r;
}

__device__ __forceinline__ float sigmoidf_(float xv) {
  float e = __expf(-fabsf(xv));
  float s = 1.0f / (1.0f + e);
  return xv >= 0.0f ? s : 1.0f - s;
}

// fast approx reciprocal (v_rcp_f32, +-1 ulp; rcp(inf)=0, rcp(1)=1)
__device__ __forceinline__ float rcpf_(float xv) {
  float r;
  asm("v_rcp_f32 %0, %1" : "=v"(r) : "v"(xv));
  return r;
}

// pack 8 fp32 -> 8 bf16 via v_cvt_pk_bf16_f32 (RNE), 4 instrs
__device__ __forceinline__ short8 cvt8(float4 f0, float4 f1) {
  union { uint_t u[4]; short8 s; } cv;
  asm("v_cvt_pk_bf16_f32 %0, %1, %2" : "=v"(cv.u[0]) : "v"(f0.x), "v"(f0.y));
  asm("v_cvt_pk_bf16_f32 %0, %1, %2" : "=v"(cv.u[1]) : "v"(f0.z), "v"(f0.w));
  asm("v_cvt_pk_bf16_f32 %0, %1, %2" : "=v"(cv.u[2]) : "v"(f1.x), "v"(f1.y));
  asm("v_cvt_pk_bf16_f32 %0, %1, %2" : "=v"(cv.u[3]) : "v"(f1.z), "v"(f1.w));
  return cv.s;
}

__device__ __forceinline__ float unpack_lo(uint_t pk) {
  return __half2float(__ushort_as_half((ushort_t)(pk & 0xFFFFu)));
}
__device__ __forceinline__ float unpack_hi(uint_t pk) {
  return __half2float(__ushort_as_half((ushort_t)(pk >> 16)));
}

// ---------------------------------------------------------------------------
// Kernel 1: pack W'' (Wz,Wh interleaved by 16-col groups) into bf16 in the
// GEMM's exact per-kstep LDS image, GRANULE-MAJOR: granule index within a
// kstep = c*512 + n  (c = 16B k-chunk 0..3, n = interleaved col 0..511).
// (proven round 3: 16-lane row-groups read contiguous granules -> 0 conflicts)
// W''[n] -> gate = (n>>4)&1 (0=Wz,1=Wh), h = (n>>5)*16 + (n&15).
// ---------------------------------------------------------------------------
__global__ void prep_w(const float* __restrict__ Wz, const float* __restrict__ Wh,
                       ushort_t* __restrict__ wsB) {
  int g = blockIdx.x * 256 + threadIdx.x;  // 16384 granules total
  if (g >= 8 * 2048) return;
  int ks = g >> 11;
  int r = g & 2047;
  int c = r >> 9;        // 0..3
  int n = r & 511;       // 0..511
  int h = (n >> 5) * 16 + (n & 15);
  const float* W = ((n >> 4) & 1) ? Wh : Wz;
  const float* src = W + (size_t)h * D_IN + ks * 32 + c * 8;
  ushort_t* dst = wsB + (size_t)g * 8;
#pragma unroll
  for (int j = 0; j < 8; ++j) dst[j] = f2bf(src[j]);
}

// ---------------------------------------------------------------------------
// Kernel 2 (round-3 structure, VALU-trimmed): BM=64 x BN=512, BK=32, 8 ksteps.
// 512 threads = 8 waves, 1(M)x8(N) -> wave tile 64x64, acc[4][4].
// LDS 72KB (A 2x4K, B 2x32K) -> 2 blocks/CU. Granule-major layout, 0 conflicts.
// A: waves 0-3 reg-stage fp32->bf16 via v_cvt_pk (T14: load early/write late).
// B: global_load_lds width=16 from granule-major wsB (L2-resident).
// ---------------------------------------------------------------------------
__global__ __launch_bounds__(512, 4) void gemm_av(
    const float* __restrict__ x, const ushort_t* __restrict__ wsB,
    const float* __restrict__ bz, const float* __restrict__ bh,
    uint_t* __restrict__ av) {
  __shared__ __align__(16) unsigned char lds[73728];
  ushort_t* As = (ushort_t*)lds;                  // 2 x 4096 B  (2048 el/buf)
  ushort_t* Bs = (ushort_t*)(lds + 8192);         // 2 x 32768 B (16384 el/buf)

  const int tid = threadIdx.x;
  const int lane = tid & 63;
  const int wid = tid >> 6;         // 0..7 = N-group
  const int m0 = blockIdx.x * 64;

  // A-stage mapping (threads 0..255): granule G = g*64 + row, g = 16B k-chunk
  const int a_row = tid & 63;
  const int a_g = tid >> 6;         // valid for tid<256
  const float* asrc = x + (size_t)(m0 + a_row) * D_IN + a_g * 8;

  f32x4 acc[4][4];
#pragma unroll
  for (int rt = 0; rt < 4; ++rt)
#pragma unroll
    for (int ct = 0; ct < 4; ++ct) {
      f32x4 z4 = {0.f, 0.f, 0.f, 0.f};
      acc[rt][ct] = z4;
    }

  // ---- prologue: stage kstep 0 into buffer 0 ----
  {
    const ushort_t* bsrc = wsB + (size_t)wid * 2048 + lane * 8;
    ushort_t* bdst = Bs + wid * 2048;
#pragma unroll
    for (int cc = 0; cc < 4; ++cc) {
      __builtin_amdgcn_global_load_lds(
          (const __attribute__((address_space(1))) void*)(bsrc + cc * 512),
          (__attribute__((address_space(3))) void*)(bdst + cc * 512), 16, 0, 0);
    }
    if (tid < 256) {
      float4 f0 = *(const float4*)(asrc);
      float4 f1 = *(const float4*)(asrc + 4);
      *(short8*)(As + tid * 8) = cvt8(f0, f1);
    }
  }
  __syncthreads();

#pragma unroll
  for (int ks = 0; ks < 8; ++ks) {
    const int cur = ks & 1;
    // 1. LDS -> register fragments (granule-major: granule = c*NROWS + idx)
    short8 afr[4], bfr[4];
    {
      const int c = lane >> 4;
      const int r16 = lane & 15;
#pragma unroll
      for (int rt = 0; rt < 4; ++rt) {
        int row = rt * 16 + r16;
        afr[rt] = *(const short8*)(As + cur * 2048 + (c * 64 + row) * 8);
      }
#pragma unroll
      for (int ct = 0; ct < 4; ++ct) {
        int n = wid * 64 + ct * 16 + r16;
        bfr[ct] = *(const short8*)(Bs + cur * 16384 + (c * 512 + n) * 8);
      }
    }
    // 2. issue next-tile staging (latency hides under MFMAs)
    float4 nf0, nf1;
    if (ks < 7) {
      const ushort_t* bsrc = wsB + (size_t)(ks + 1) * 16384 + wid * 2048 + lane * 8;
      ushort_t* bdst = Bs + (cur ^ 1) * 16384 + wid * 2048;
#pragma unroll
      for (int cc = 0; cc < 4; ++cc) {
        __builtin_amdgcn_global_load_lds(
            (const __attribute__((address_space(1))) void*)(bsrc + cc * 512),
            (__attribute__((address_space(3))) void*)(bdst + cc * 512), 16, 0, 0);
      }
      if (tid < 256) {
        nf0 = *(const float4*)(asrc + (ks + 1) * 32);
        nf1 = *(const float4*)(asrc + (ks + 1) * 32 + 4);
      }
    }
    // 3. MFMAs
#pragma unroll
    for (int rt = 0; rt < 4; ++rt)
#pragma unroll
      for (int ct = 0; ct < 4; ++ct)
        acc[rt][ct] = __builtin_amdgcn_mfma_f32_16x16x32_bf16(
            afr[rt], bfr[ct], acc[rt][ct], 0, 0, 0);
    // 4. A write-late (reg->LDS after compute)
    if (ks < 7 && tid < 256) {
      *(short8*)(As + (cur ^ 1) * 2048 + tid * 8) = cvt8(nf0, nf1);
    }
    __syncthreads();
  }

  // ---- epilogue: gate math (branch-safe fast sigmoid), pack half2(a,v) ----
  const int col16 = lane & 15;
  const int rgrp = lane >> 4;
#pragma unroll
  for (int i = 0; i < 2; ++i) {
    int hh = (wid * 2 + i) * 16 + col16;
    float bzv = bz[hh];
    float bhv = bh[hh];
#pragma unroll
    for (int rt = 0; rt < 4; ++rt) {
#pragma unroll
      for (int j = 0; j < 4; ++j) {
        int row = m0 + rt * 16 + rgrp * 4 + j;
        float kv = acc[rt][2 * i][j] + bzv;
        float pv = acc[rt][2 * i + 1][j] + bhv;
        // a = sigma(-k) = 1/(1+e^k): e^k=inf -> rcp(inf)=0; e^k=0 -> 1. Safe.
        float ek = __expf(kv);
        float a = rcpf_(1.0f + ek);
        float z = 1.0f - a;               // sigma(k)
        float ep = __expf(pv);
        float gn = 1.0f - rcpf_(1.0f + ep);  // sigma(p), exact at both tails
        float gg = (pv >= 0.0f) ? (pv + 0.5f) : gn;
        float vv = z * gg;
        uint_t pk = (uint_t)__half_as_ushort(__float2half_rn(a)) |
                    ((uint_t)__half_as_ushort(__float2half_rn(vv)) << 16);
        av[(size_t)row * H_SZ + hh] = pk;
      }
    }
  }
}

// ---------------------------------------------------------------------------
// Two-level scan (proven rounds 2-3): affine composition per CHUNK.
// Phase 1: per (b, chunk): compose 64 steps -> (A, V). 2048 blocks x 256 thr.
// ---------------------------------------------------------------------------
__global__ __launch_bounds__(256) void chunk_reduce(
    const uint_t* __restrict__ av, float2* __restrict__ cAV) {
  const int b = blockIdx.x >> 6;
  const int c = blockIdx.x & 63;
  const int h = threadIdx.x;
  const uint_t* p = av + ((size_t)b * T_SZ + c * CHUNK) * H_SZ + h;

  uint_t buf[CHUNK];
#pragma unroll
  for (int s = 0; s < CHUNK; ++s) buf[s] = p[(size_t)s * H_SZ];

  float A = 1.0f, V = 0.0f;
#pragma unroll
  for (int s = 0; s < CHUNK; ++s) {
    float a = unpack_lo(buf[s]);
    float v = unpack_hi(buf[s]);
    A = a * A;
    V = fmaf(a, V, v);
  }
  float2 r; r.x = A; r.y = V;
  cAV[((size_t)b * NCHUNK + c) * H_SZ + h] = r;
}

// ---------------------------------------------------------------------------
// Phase 2: per (b,h): sequentially compose chunk summaries from g(h0),
// writing the INCOMING h for each chunk. 32 blocks x 256 thr.
// ---------------------------------------------------------------------------
__global__ __launch_bounds__(256) void chunk_carry(
    const float* __restrict__ h0, const float2* __restrict__ cAV,
    float* __restrict__ hb) {
  const int b = blockIdx.x;
  const int h = threadIdx.x;
  float v0 = h0[b * H_SZ + h];
  float hc = (v0 >= 0.0f) ? (v0 + 0.5f) : sigmoidf_(v0);

  const float2* p = cAV + (size_t)b * NCHUNK * H_SZ + h;
  float* o = hb + (size_t)b * NCHUNK * H_SZ + h;

  float2 buf[NCHUNK];
#pragma unroll
  for (int c = 0; c < NCHUNK; ++c) buf[c] = p[(size_t)c * H_SZ];

#pragma unroll
  for (int c = 0; c < NCHUNK; ++c) {
    o[(size_t)c * H_SZ] = hc;
    hc = fmaf(buf[c].x, hc, buf[c].y);
  }
}

// ---------------------------------------------------------------------------
// Phase 3: per (b, chunk): start from carry, re-scan av, write fp32 out.
// av may alias out (in-place fallback): per-thread loads strictly precede
// stores to the same addresses; no __restrict__ on av/out.
// ---------------------------------------------------------------------------
__global__ __launch_bounds__(256) void chunk_scan_out(
    const uint_t* av, const float* __restrict__ hb, float* out) {
  const int b = blockIdx.x >> 6;
  const int c = blockIdx.x & 63;
  const int h = threadIdx.x;

  float hc = hb[((size_t)b * NCHUNK + c) * H_SZ + h];
  const uint_t* p = av + ((size_t)b * T_SZ + c * CHUNK) * H_SZ + h;
  float* o = out + ((size_t)b * T_SZ + c * CHUNK) * H_SZ + h;

  uint_t buf[CHUNK];
#pragma unroll
  for (int s = 0; s < CHUNK; ++s) buf[s] = p[(size_t)s * H_SZ];

#pragma unroll
  for (int s = 0; s < CHUNK; ++s) {
    float a = unpack_lo(buf[s]);
    float v = unpack_hi(buf[s]);
    hc = fmaf(a, hc, v);
    o[(size_t)s * H_SZ] = hc;
  }
}

// Fallback: fully-sequential scan (only if ws too small for summaries).
__global__ __launch_bounds__(64) void scan_seq(const float* __restrict__ h0,
                                               const uint_t* av, float* out) {
  const int b = blockIdx.x >> 2;
  const int hg = blockIdx.x & 3;
  const int h = hg * 64 + threadIdx.x;

  float v0 = h0[b * H_SZ + h];
  float hc = (v0 >= 0.0f) ? (v0 + 0.5f) : sigmoidf_(v0);

  const uint_t* p = av + (size_t)b * T_SZ * H_SZ + h;
  float* o = out + (size_t)b * T_SZ * H_SZ + h;

  uint_t buf[32];
#pragma unroll
  for (int d = 0; d < 32; ++d) buf[d] = p[(size_t)d * H_SZ];

  for (int t0 = 0; t0 < T_SZ; t0 += 32) {
#pragma unroll
    for (int d = 0; d < 32; ++d) {
      int t = t0 + d;
      uint_t pk = buf[d];
      int tn = t + 32;
      if (tn < T_SZ) buf[d] = p[(size_t)tn * H_SZ];
      hc = fmaf(unpack_lo(pk), hc, unpack_hi(pk));
      o[(size_t)t * H_SZ] = hc;
    }
  }
}

extern "C" void kernel_launch(void* const* d_in, const int* in_sizes, int n_in,
                              void* d_out, int out_size, void* d_ws, size_t ws_size,
                              hipStream_t stream) {
  const float* x  = (const float*)d_in[0];
  const float* h0 = (const float*)d_in[1];
  const float* Wz = (const float*)d_in[2];
  const float* bz = (const float*)d_in[3];
  const float* Wh = (const float*)d_in[4];
  const float* bh = (const float*)d_in[5];
  float* out = (float*)d_out;

  // ws layout: [wsB 256K][cAV 4M][hb 2M][pad to 8M][av 134M if it fits]
  const size_t wsBBytes = 262144;
  const size_t cavBytes = (size_t)B_SZ * NCHUNK * H_SZ * 8;   // 4 MiB
  const size_t hbBytes  = (size_t)B_SZ * NCHUNK * H_SZ * 4;   // 2 MiB
  const size_t avOff    = 8388608;
  const size_t avBytes  = (size_t)M_SZ * H_SZ * 4;            // 134 MiB

  ushort_t* wsB = (ushort_t*)d_ws;
  float2* cAV = (float2*)((char*)d_ws + wsBBytes);
  float* hb   = (float*)((char*)d_ws + wsBBytes + cavBytes);

  const bool haveSummaries = ws_size >= wsBBytes + cavBytes + hbBytes;
  uint_t* av;
  if (ws_size >= avOff + avBytes) {
    av = (uint_t*)((char*)d_ws + avOff);
  } else {
    av = (uint_t*)d_out;  // in-place: scan reads av[t] before writing h[t]
  }

  prep_w<<<64, 256, 0, stream>>>(Wz, Wh, wsB);
  gemm_av<<<M_SZ / 64, 512, 0, stream>>>(x, wsB, bz, bh, av);
  if (haveSummaries) {
    chunk_reduce<<<B_SZ * NCHUNK, 256, 0, stream>>>(av, cAV);
    chunk_carry<<<B_SZ, 256, 0, stream>>>(h0, cAV, hb);
    chunk_scan_out<<<B_SZ * NCHUNK, 256, 0, stream>>>(av, hb, out);
  } else {
    scan_seq<<<B_SZ * 4, 64, 0, stream>>>(h0, av, out);
  }
}

// Round 7
// 203.325 us; speedup vs baseline: 1.0894x; 1.0894x over previous
//
#include <hip/hip_runtime.h>
#include <hip/hip_fp16.h>

typedef __attribute__((ext_vector_type(8))) short short8;
typedef __attribute__((ext_vector_type(4))) float f32x4;
typedef unsigned short ushort_t;
typedef unsigned int uint_t;

#define B_SZ 32
#define T_SZ 4096
#define D_IN 256
#define H_SZ 256
#define M_SZ (B_SZ * T_SZ)  // 131072
#define CHUNK 64
#define NCHUNK (T_SZ / CHUNK)  // 64

__device__ __forceinline__ ushort_t f2bf(float f) {
  unsigned int u = __float_as_uint(f);
  unsigned int r = (u + 0x7FFFu + ((u >> 16) & 1u)) >> 16;
  return (ushort_t)r;
}

__device__ __forceinline__ float sigmoidf_(float xv) {
  float e = __expf(-fabsf(xv));
  float s = 1.0f / (1.0f + e);
  return xv >= 0.0f ? s : 1.0f - s;
}

__device__ __forceinline__ float unpack_lo(uint_t pk) {
  return __half2float(__ushort_as_half((ushort_t)(pk & 0xFFFFu)));
}
__device__ __forceinline__ float unpack_hi(uint_t pk) {
  return __half2float(__ushort_as_half((ushort_t)(pk >> 16)));
}

// ---------------------------------------------------------------------------
// Kernel 1: pack W'' into bf16 in B-FRAGMENT order (direct global->VGPR GEMM
// consumption; proven round 5). Granule g = ((grp*8 + ks)*64 + lane), 16 B:
//   grp = wid*4 + ct (0..31), ks = 0..7, lane = 0..63.
// Content: W''[n][k0..k0+7], n = grp*16 + (lane&15), k0 = ks*32 + (lane>>4)*8.
// W''[n]: gate = (n>>4)&1 (0=Wz,1=Wh), h = (n>>5)*16 + (n&15).
// ---------------------------------------------------------------------------
__global__ void prep_w(const float* __restrict__ Wz, const float* __restrict__ Wh,
                       ushort_t* __restrict__ wsB) {
  int g = blockIdx.x * 256 + threadIdx.x;  // 16384 granules
  if (g >= 32 * 8 * 64) return;
  int lane = g & 63;
  int ks = (g >> 6) & 7;
  int grp = g >> 9;
  int c16 = lane & 15;
  int h = (grp >> 1) * 16 + c16;
  int k0 = ks * 32 + (lane >> 4) * 8;
  const float* W = (grp & 1) ? Wh : Wz;
  const float* src = W + (size_t)h * D_IN + k0;
  ushort_t* dst = wsB + (size_t)g * 8;
#pragma unroll
  for (int j = 0; j < 8; ++j) dst[j] = f2bf(src[j]);
}

// ---------------------------------------------------------------------------
// Kernel 2: BM=64 x BN=512, BK=32, 8 ksteps. 512 threads = 8 waves, 1(M)x8(N)
// -> wave tile 64x64, acc[4][4].
// A: round-3 path verbatim — waves 0-3 reg-stage fp32->bf16 (f2bf) into
//    granule-major LDS (2x4KB double buffer), T14 load-early/write-late.
// B: NO LDS. Per-kstep direct global->VGPR b128 loads from frag-ordered wsB
//    (L2-resident), register double-buffered: bfr[(ks+1)&1] issued during
//    kstep ks; the compiler's vmcnt(0) at __syncthreads IS the completion
//    guarantee, so MFMAs never wait on B and the barrier drain carries only
//    A's 8KB. LDS 8KB total -> ~3 blocks/CU co-residency hides the A drain.
// ---------------------------------------------------------------------------
__global__ __launch_bounds__(512, 4) void gemm_av(
    const float* __restrict__ x, const ushort_t* __restrict__ wsB,
    const float* __restrict__ bz, const float* __restrict__ bh,
    uint_t* __restrict__ av) {
  __shared__ __align__(16) unsigned char lds[8192];
  ushort_t* As = (ushort_t*)lds;  // 2 x 4096 B (2048 bf16 per buffer)

  const int tid = threadIdx.x;
  const int lane = tid & 63;
  const int wid = tid >> 6;         // 0..7 = N-group
  const int m0 = blockIdx.x * 64;

  // A-stage mapping (threads 0..255): granule G = g*64 + row, g = 16B k-chunk
  const int a_row = tid & 63;
  const int a_g = tid >> 6;         // valid for tid<256
  const float* asrc = x + (size_t)(m0 + a_row) * D_IN + a_g * 8;

  // B frag granules, 16 B each
  const short8* bgr = (const short8*)wsB;

  f32x4 acc[4][4];
#pragma unroll
  for (int rt = 0; rt < 4; ++rt)
#pragma unroll
    for (int ct = 0; ct < 4; ++ct) {
      f32x4 z4 = {0.f, 0.f, 0.f, 0.f};
      acc[rt][ct] = z4;
    }

  short8 bfr[2][4];

  // ---- prologue: B frags for ks=0 + A kstep 0 into buffer 0 ----
  {
#pragma unroll
    for (int ct = 0; ct < 4; ++ct)
      bfr[0][ct] = bgr[((wid * 4 + ct) * 8 + 0) * 64 + lane];
    if (tid < 256) {
      float4 f0 = *(const float4*)(asrc);
      float4 f1 = *(const float4*)(asrc + 4);
      union { ushort_t e[8]; short8 s; } cv;
      cv.e[0] = f2bf(f0.x); cv.e[1] = f2bf(f0.y);
      cv.e[2] = f2bf(f0.z); cv.e[3] = f2bf(f0.w);
      cv.e[4] = f2bf(f1.x); cv.e[5] = f2bf(f1.y);
      cv.e[6] = f2bf(f1.z); cv.e[7] = f2bf(f1.w);
      *(short8*)(As + tid * 8) = cv.s;
    }
  }
  __syncthreads();

#pragma unroll
  for (int ks = 0; ks < 8; ++ks) {
    const int cur = ks & 1;
    // 1. A fragments from LDS (granule-major: granule = c*64 + row)
    short8 afr[4];
    {
      const int c = lane >> 4;
      const int r16 = lane & 15;
#pragma unroll
      for (int rt = 0; rt < 4; ++rt) {
        int row = rt * 16 + r16;
        afr[rt] = *(const short8*)(As + cur * 2048 + (c * 64 + row) * 8);
      }
    }
    // 2. issue next-kstep loads (B->regs, A->regs); complete by the barrier
    float4 nf0, nf1;
    if (ks < 7) {
#pragma unroll
      for (int ct = 0; ct < 4; ++ct)
        bfr[cur ^ 1][ct] = bgr[((wid * 4 + ct) * 8 + (ks + 1)) * 64 + lane];
      if (tid < 256) {
        nf0 = *(const float4*)(asrc + (ks + 1) * 32);
        nf1 = *(const float4*)(asrc + (ks + 1) * 32 + 4);
      }
    }
    // 3. MFMAs (B from regs loaded last kstep — already drained, no wait)
#pragma unroll
    for (int rt = 0; rt < 4; ++rt)
#pragma unroll
      for (int ct = 0; ct < 4; ++ct)
        acc[rt][ct] = __builtin_amdgcn_mfma_f32_16x16x32_bf16(
            afr[rt], bfr[cur][ct], acc[rt][ct], 0, 0, 0);
    // 4. A write-late (reg->LDS after compute)
    if (ks < 7 && tid < 256) {
      union { ushort_t e[8]; short8 s; } cv;
      cv.e[0] = f2bf(nf0.x); cv.e[1] = f2bf(nf0.y);
      cv.e[2] = f2bf(nf0.z); cv.e[3] = f2bf(nf0.w);
      cv.e[4] = f2bf(nf1.x); cv.e[5] = f2bf(nf1.y);
      cv.e[6] = f2bf(nf1.z); cv.e[7] = f2bf(nf1.w);
      *(short8*)(As + (cur ^ 1) * 2048 + tid * 8) = cv.s;
    }
    __syncthreads();
  }

  // ---- epilogue (round-3 verbatim): gate math, pack half2(a,v) ----
  const int col16 = lane & 15;
  const int rgrp = lane >> 4;
#pragma unroll
  for (int i = 0; i < 2; ++i) {
    int hh = (wid * 2 + i) * 16 + col16;
    float bzv = bz[hh];
    float bhv = bh[hh];
#pragma unroll
    for (int rt = 0; rt < 4; ++rt) {
#pragma unroll
      for (int j = 0; j < 4; ++j) {
        int row = m0 + rt * 16 + rgrp * 4 + j;
        float kv = acc[rt][2 * i][j] + bzv;
        float pv = acc[rt][2 * i + 1][j] + bhv;
        float a = sigmoidf_(-kv);       // 1 - sigmoid(k)
        float z = 1.0f - a;             // sigmoid(k)
        float gg = (pv >= 0.0f) ? (pv + 0.5f) : sigmoidf_(pv);
        float vv = z * gg;
        uint_t pk = (uint_t)__half_as_ushort(__float2half_rn(a)) |
                    ((uint_t)__half_as_ushort(__float2half_rn(vv)) << 16);
        av[(size_t)row * H_SZ + hh] = pk;
      }
    }
  }
}

// ---------------------------------------------------------------------------
// Two-level scan (proven rounds 2-3): affine composition per CHUNK.
// Phase 1: per (b, chunk): compose 64 steps -> (A, V). 2048 blocks x 256 thr.
// ---------------------------------------------------------------------------
__global__ __launch_bounds__(256) void chunk_reduce(
    const uint_t* __restrict__ av, float2* __restrict__ cAV) {
  const int b = blockIdx.x >> 6;
  const int c = blockIdx.x & 63;
  const int h = threadIdx.x;
  const uint_t* p = av + ((size_t)b * T_SZ + c * CHUNK) * H_SZ + h;

  uint_t buf[CHUNK];
#pragma unroll
  for (int s = 0; s < CHUNK; ++s) buf[s] = p[(size_t)s * H_SZ];

  float A = 1.0f, V = 0.0f;
#pragma unroll
  for (int s = 0; s < CHUNK; ++s) {
    float a = unpack_lo(buf[s]);
    float v = unpack_hi(buf[s]);
    A = a * A;
    V = fmaf(a, V, v);
  }
  float2 r; r.x = A; r.y = V;
  cAV[((size_t)b * NCHUNK + c) * H_SZ + h] = r;
}

// ---------------------------------------------------------------------------
// Phase 2: per (b,h): sequentially compose chunk summaries from g(h0),
// writing the INCOMING h for each chunk. 32 blocks x 256 thr.
// ---------------------------------------------------------------------------
__global__ __launch_bounds__(256) void chunk_carry(
    const float* __restrict__ h0, const float2* __restrict__ cAV,
    float* __restrict__ hb) {
  const int b = blockIdx.x;
  const int h = threadIdx.x;
  float v0 = h0[b * H_SZ + h];
  float hc = (v0 >= 0.0f) ? (v0 + 0.5f) : sigmoidf_(v0);

  const float2* p = cAV + (size_t)b * NCHUNK * H_SZ + h;
  float* o = hb + (size_t)b * NCHUNK * H_SZ + h;

  float2 buf[NCHUNK];
#pragma unroll
  for (int c = 0; c < NCHUNK; ++c) buf[c] = p[(size_t)c * H_SZ];

#pragma unroll
  for (int c = 0; c < NCHUNK; ++c) {
    o[(size_t)c * H_SZ] = hc;
    hc = fmaf(buf[c].x, hc, buf[c].y);
  }
}

// ---------------------------------------------------------------------------
// Phase 3: per (b, chunk): start from carry, re-scan av, write fp32 out.
// av may alias out (in-place fallback): per-thread loads strictly precede
// stores to the same addresses; no __restrict__ on av/out.
// ---------------------------------------------------------------------------
__global__ __launch_bounds__(256) void chunk_scan_out(
    const uint_t* av, const float* __restrict__ hb, float* out) {
  const int b = blockIdx.x >> 6;
  const int c = blockIdx.x & 63;
  const int h = threadIdx.x;

  float hc = hb[((size_t)b * NCHUNK + c) * H_SZ + h];
  const uint_t* p = av + ((size_t)b * T_SZ + c * CHUNK) * H_SZ + h;
  float* o = out + ((size_t)b * T_SZ + c * CHUNK) * H_SZ + h;

  uint_t buf[CHUNK];
#pragma unroll
  for (int s = 0; s < CHUNK; ++s) buf[s] = p[(size_t)s * H_SZ];

#pragma unroll
  for (int s = 0; s < CHUNK; ++s) {
    float a = unpack_lo(buf[s]);
    float v = unpack_hi(buf[s]);
    hc = fmaf(a, hc, v);
    o[(size_t)s * H_SZ] = hc;
  }
}

// Fallback: fully-sequential scan (only if ws too small for summaries).
__global__ __launch_bounds__(64) void scan_seq(const float* __restrict__ h0,
                                               const uint_t* av, float* out) {
  const int b = blockIdx.x >> 2;
  const int hg = blockIdx.x & 3;
  const int h = hg * 64 + threadIdx.x;

  float v0 = h0[b * H_SZ + h];
  float hc = (v0 >= 0.0f) ? (v0 + 0.5f) : sigmoidf_(v0);

  const uint_t* p = av + (size_t)b * T_SZ * H_SZ + h;
  float* o = out + (size_t)b * T_SZ * H_SZ + h;

  uint_t buf[32];
#pragma unroll
  for (int d = 0; d < 32; ++d) buf[d] = p[(size_t)d * H_SZ];

  for (int t0 = 0; t0 < T_SZ; t0 += 32) {
#pragma unroll
    for (int d = 0; d < 32; ++d) {
      int t = t0 + d;
      uint_t pk = buf[d];
      int tn = t + 32;
      if (tn < T_SZ) buf[d] = p[(size_t)tn * H_SZ];
      hc = fmaf(unpack_lo(pk), hc, unpack_hi(pk));
      o[(size_t)t * H_SZ] = hc;
    }
  }
}

extern "C" void kernel_launch(void* const* d_in, const int* in_sizes, int n_in,
                              void* d_out, int out_size, void* d_ws, size_t ws_size,
                              hipStream_t stream) {
  const float* x  = (const float*)d_in[0];
  const float* h0 = (const float*)d_in[1];
  const float* Wz = (const float*)d_in[2];
  const float* bz = (const float*)d_in[3];
  const float* Wh = (const float*)d_in[4];
  const float* bh = (const float*)d_in[5];
  float* out = (float*)d_out;

  // ws layout: [wsB 256K][cAV 4M][hb 2M][pad to 8M][av 134M if it fits]
  const size_t wsBBytes = 262144;
  const size_t cavBytes = (size_t)B_SZ * NCHUNK * H_SZ * 8;   // 4 MiB
  const size_t hbBytes  = (size_t)B_SZ * NCHUNK * H_SZ * 4;   // 2 MiB
  const size_t avOff    = 8388608;
  const size_t avBytes  = (size_t)M_SZ * H_SZ * 4;            // 134 MiB

  ushort_t* wsB = (ushort_t*)d_ws;
  float2* cAV = (float2*)((char*)d_ws + wsBBytes);
  float* hb   = (float*)((char*)d_ws + wsBBytes + cavBytes);

  const bool haveSummaries = ws_size >= wsBBytes + cavBytes + hbBytes;
  uint_t* av;
  if (ws_size >= avOff + avBytes) {
    av = (uint_t*)((char*)d_ws + avOff);
  } else {
    av = (uint_t*)d_out;  // in-place: scan reads av[t] before writing h[t]
  }

  prep_w<<<64, 256, 0, stream>>>(Wz, Wh, wsB);
  gemm_av<<<M_SZ / 64, 512, 0, stream>>>(x, wsB, bz, bh, av);
  if (haveSummaries) {
    chunk_reduce<<<B_SZ * NCHUNK, 256, 0, stream>>>(av, cAV);
    chunk_carry<<<B_SZ, 256, 0, stream>>>(h0, cAV, hb);
    chunk_scan_out<<<B_SZ * NCHUNK, 256, 0, stream>>>(av, hb, out);
  } else {
    scan_seq<<<B_SZ * 4, 64, 0, stream>>>(h0, av, out);
  }
}

// Round 8
// 196.200 us; speedup vs baseline: 1.1289x; 1.0363x over previous
//
#include <hip/hip_runtime.h>
#include <hip/hip_fp16.h>

typedef __attribute__((ext_vector_type(8))) short short8;
typedef __attribute__((ext_vector_type(4))) float f32x4;
typedef unsigned short ushort_t;
typedef unsigned int uint_t;

#define B_SZ 32
#define T_SZ 4096
#define D_IN 256
#define H_SZ 256
#define M_SZ (B_SZ * T_SZ)  // 131072
#define CHUNK 64
#define NCHUNK (T_SZ / CHUNK)  // 64

__device__ __forceinline__ ushort_t f2bf(float f) {
  unsigned int u = __float_as_uint(f);
  unsigned int r = (u + 0x7FFFu + ((u >> 16) & 1u)) >> 16;
  return (ushort_t)r;
}

__device__ __forceinline__ float sigmoidf_(float xv) {
  float e = __expf(-fabsf(xv));
  float s = 1.0f / (1.0f + e);
  return xv >= 0.0f ? s : 1.0f - s;
}

__device__ __forceinline__ float unpack_lo(uint_t pk) {
  return __half2float(__ushort_as_half((ushort_t)(pk & 0xFFFFu)));
}
__device__ __forceinline__ float unpack_hi(uint_t pk) {
  return __half2float(__ushort_as_half((ushort_t)(pk >> 16)));
}

// ---------------------------------------------------------------------------
// Kernel 1 (round-3 verbatim): pack W'' (Wz,Wh interleaved by 16-col groups)
// into bf16 in the GEMM's per-kstep LDS image, GRANULE-MAJOR: granule index
// within a kstep = c*512 + n (c = 16B k-chunk 0..3, n = interleaved col).
// W''[n] -> gate = (n>>4)&1 (0=Wz,1=Wh), h = (n>>5)*16 + (n&15).
// ---------------------------------------------------------------------------
__global__ void prep_w(const float* __restrict__ Wz, const float* __restrict__ Wh,
                       ushort_t* __restrict__ wsB) {
  int g = blockIdx.x * 256 + threadIdx.x;  // 16384 granules total
  if (g >= 8 * 2048) return;
  int ks = g >> 11;
  int r = g & 2047;
  int c = r >> 9;        // 0..3
  int n = r & 511;       // 0..511
  int h = (n >> 5) * 16 + (n & 15);
  const float* W = ((n >> 4) & 1) ? Wh : Wz;
  const float* src = W + (size_t)h * D_IN + ks * 32 + c * 8;
  ushort_t* dst = wsB + (size_t)g * 8;
#pragma unroll
  for (int j = 0; j < 8; ++j) dst[j] = f2bf(src[j]);
}

// ---------------------------------------------------------------------------
// Kernel 2 (round-3 structure verbatim; ONLY the epilogue gate math changed):
// BM=64 x BN=512, BK=32, 8 ksteps. 512 threads = 8 waves, 1(M)x8(N) ->
// wave tile 64x64, acc[4][4]. LDS 72KB (A 2x4K, B 2x32K) -> 2 blocks/CU.
// Granule-major layout, 0 bank conflicts.
// A: waves 0-3 reg-stage fp32->bf16 via f2bf (T14 load-early/write-late).
// B: global_load_lds width=16 from granule-major wsB (L2-resident).
// Epilogue: fast sigmoid via __builtin_amdgcn_rcpf (+-1 ulp; rcp(inf)=0 and
// rcp(1)=1 make the unguarded form exact at both saturation ends), and
// g(p) = max(p+0.5, sigma(p)) (exact identity: sigma(p)-p-0.5 is strictly
// decreasing with zero at p=0).
// ---------------------------------------------------------------------------
__global__ __launch_bounds__(512, 4) void gemm_av(
    const float* __restrict__ x, const ushort_t* __restrict__ wsB,
    const float* __restrict__ bz, const float* __restrict__ bh,
    uint_t* __restrict__ av) {
  __shared__ __align__(16) unsigned char lds[73728];
  ushort_t* As = (ushort_t*)lds;                  // 2 x 4096 B  (2048 el/buf)
  ushort_t* Bs = (ushort_t*)(lds + 8192);         // 2 x 32768 B (16384 el/buf)

  const int tid = threadIdx.x;
  const int lane = tid & 63;
  const int wid = tid >> 6;         // 0..7 = N-group
  const int m0 = blockIdx.x * 64;

  // A-stage mapping (threads 0..255): granule G = g*64 + row, g = 16B k-chunk
  const int a_row = tid & 63;
  const int a_g = tid >> 6;         // valid for tid<256
  const float* asrc = x + (size_t)(m0 + a_row) * D_IN + a_g * 8;

  f32x4 acc[4][4];
#pragma unroll
  for (int rt = 0; rt < 4; ++rt)
#pragma unroll
    for (int ct = 0; ct < 4; ++ct) {
      f32x4 z4 = {0.f, 0.f, 0.f, 0.f};
      acc[rt][ct] = z4;
    }

  // ---- prologue: stage kstep 0 into buffer 0 ----
  {
    const ushort_t* bsrc = wsB + (size_t)wid * 2048 + lane * 8;
    ushort_t* bdst = Bs + wid * 2048;
#pragma unroll
    for (int cc = 0; cc < 4; ++cc) {
      __builtin_amdgcn_global_load_lds(
          (const __attribute__((address_space(1))) void*)(bsrc + cc * 512),
          (__attribute__((address_space(3))) void*)(bdst + cc * 512), 16, 0, 0);
    }
    if (tid < 256) {
      float4 f0 = *(const float4*)(asrc);
      float4 f1 = *(const float4*)(asrc + 4);
      union { ushort_t e[8]; short8 s; } cv;
      cv.e[0] = f2bf(f0.x); cv.e[1] = f2bf(f0.y);
      cv.e[2] = f2bf(f0.z); cv.e[3] = f2bf(f0.w);
      cv.e[4] = f2bf(f1.x); cv.e[5] = f2bf(f1.y);
      cv.e[6] = f2bf(f1.z); cv.e[7] = f2bf(f1.w);
      *(short8*)(As + tid * 8) = cv.s;
    }
  }
  __syncthreads();

#pragma unroll
  for (int ks = 0; ks < 8; ++ks) {
    const int cur = ks & 1;
    // 1. LDS -> register fragments (granule-major: granule = c*NROWS + idx)
    short8 afr[4], bfr[4];
    {
      const int c = lane >> 4;
      const int r16 = lane & 15;
#pragma unroll
      for (int rt = 0; rt < 4; ++rt) {
        int row = rt * 16 + r16;
        afr[rt] = *(const short8*)(As + cur * 2048 + (c * 64 + row) * 8);
      }
#pragma unroll
      for (int ct = 0; ct < 4; ++ct) {
        int n = wid * 64 + ct * 16 + r16;
        bfr[ct] = *(const short8*)(Bs + cur * 16384 + (c * 512 + n) * 8);
      }
    }
    // 2. issue next-tile staging (latency hides under MFMAs)
    float4 nf0, nf1;
    if (ks < 7) {
      const ushort_t* bsrc = wsB + (size_t)(ks + 1) * 16384 + wid * 2048 + lane * 8;
      ushort_t* bdst = Bs + (cur ^ 1) * 16384 + wid * 2048;
#pragma unroll
      for (int cc = 0; cc < 4; ++cc) {
        __builtin_amdgcn_global_load_lds(
            (const __attribute__((address_space(1))) void*)(bsrc + cc * 512),
            (__attribute__((address_space(3))) void*)(bdst + cc * 512), 16, 0, 0);
      }
      if (tid < 256) {
        nf0 = *(const float4*)(asrc + (ks + 1) * 32);
        nf1 = *(const float4*)(asrc + (ks + 1) * 32 + 4);
      }
    }
    // 3. MFMAs
#pragma unroll
    for (int rt = 0; rt < 4; ++rt)
#pragma unroll
      for (int ct = 0; ct < 4; ++ct)
        acc[rt][ct] = __builtin_amdgcn_mfma_f32_16x16x32_bf16(
            afr[rt], bfr[ct], acc[rt][ct], 0, 0, 0);
    // 4. A write-late (reg->LDS after compute)
    if (ks < 7 && tid < 256) {
      union { ushort_t e[8]; short8 s; } cv;
      cv.e[0] = f2bf(nf0.x); cv.e[1] = f2bf(nf0.y);
      cv.e[2] = f2bf(nf0.z); cv.e[3] = f2bf(nf0.w);
      cv.e[4] = f2bf(nf1.x); cv.e[5] = f2bf(nf1.y);
      cv.e[6] = f2bf(nf1.z); cv.e[7] = f2bf(nf1.w);
      *(short8*)(As + (cur ^ 1) * 2048 + tid * 8) = cv.s;
    }
    __syncthreads();
  }

  // ---- epilogue: fast gate math (THE one change vs round 3) ----
  const int col16 = lane & 15;
  const int rgrp = lane >> 4;
#pragma unroll
  for (int i = 0; i < 2; ++i) {
    int hh = (wid * 2 + i) * 16 + col16;
    float bzv = bz[hh];
    float bhv = bh[hh];
#pragma unroll
    for (int rt = 0; rt < 4; ++rt) {
#pragma unroll
      for (int j = 0; j < 4; ++j) {
        int row = m0 + rt * 16 + rgrp * 4 + j;
        float kv = acc[rt][2 * i][j] + bzv;
        float pv = acc[rt][2 * i + 1][j] + bhv;
        // a = sigma(-k) = 1/(1+e^k): e^k=inf -> rcp=0; e^k=0 -> rcp(1)=1.
        float a = __builtin_amdgcn_rcpf(1.0f + __expf(kv));
        float z = 1.0f - a;                         // sigma(k)
        // g(p) = max(p+0.5, sigma(p)); sigma(p) = 1 - 1/(1+e^p)
        float gsig = 1.0f - __builtin_amdgcn_rcpf(1.0f + __expf(pv));
        float gg = fmaxf(pv + 0.5f, gsig);
        float vv = z * gg;
        uint_t pk = (uint_t)__half_as_ushort(__float2half_rn(a)) |
                    ((uint_t)__half_as_ushort(__float2half_rn(vv)) << 16);
        av[(size_t)row * H_SZ + hh] = pk;
      }
    }
  }
}

// ---------------------------------------------------------------------------
// Two-level scan (proven rounds 2-3): affine composition per CHUNK.
// Phase 1: per (b, chunk): compose 64 steps -> (A, V). 2048 blocks x 256 thr.
// ---------------------------------------------------------------------------
__global__ __launch_bounds__(256) void chunk_reduce(
    const uint_t* __restrict__ av, float2* __restrict__ cAV) {
  const int b = blockIdx.x >> 6;
  const int c = blockIdx.x & 63;
  const int h = threadIdx.x;
  const uint_t* p = av + ((size_t)b * T_SZ + c * CHUNK) * H_SZ + h;

  uint_t buf[CHUNK];
#pragma unroll
  for (int s = 0; s < CHUNK; ++s) buf[s] = p[(size_t)s * H_SZ];

  float A = 1.0f, V = 0.0f;
#pragma unroll
  for (int s = 0; s < CHUNK; ++s) {
    float a = unpack_lo(buf[s]);
    float v = unpack_hi(buf[s]);
    A = a * A;
    V = fmaf(a, V, v);
  }
  float2 r; r.x = A; r.y = V;
  cAV[((size_t)b * NCHUNK + c) * H_SZ + h] = r;
}

// ---------------------------------------------------------------------------
// Phase 2: per (b,h): sequentially compose chunk summaries from g(h0),
// writing the INCOMING h for each chunk. 32 blocks x 256 thr.
// ---------------------------------------------------------------------------
__global__ __launch_bounds__(256) void chunk_carry(
    const float* __restrict__ h0, const float2* __restrict__ cAV,
    float* __restrict__ hb) {
  const int b = blockIdx.x;
  const int h = threadIdx.x;
  float v0 = h0[b * H_SZ + h];
  float hc = (v0 >= 0.0f) ? (v0 + 0.5f) : sigmoidf_(v0);

  const float2* p = cAV + (size_t)b * NCHUNK * H_SZ + h;
  float* o = hb + (size_t)b * NCHUNK * H_SZ + h;

  float2 buf[NCHUNK];
#pragma unroll
  for (int c = 0; c < NCHUNK; ++c) buf[c] = p[(size_t)c * H_SZ];

#pragma unroll
  for (int c = 0; c < NCHUNK; ++c) {
    o[(size_t)c * H_SZ] = hc;
    hc = fmaf(buf[c].x, hc, buf[c].y);
  }
}

// ---------------------------------------------------------------------------
// Phase 3: per (b, chunk): start from carry, re-scan av, write fp32 out.
// av may alias out (in-place fallback): per-thread loads strictly precede
// stores to the same addresses; no __restrict__ on av/out.
// ---------------------------------------------------------------------------
__global__ __launch_bounds__(256) void chunk_scan_out(
    const uint_t* av, const float* __restrict__ hb, float* out) {
  const int b = blockIdx.x >> 6;
  const int c = blockIdx.x & 63;
  const int h = threadIdx.x;

  float hc = hb[((size_t)b * NCHUNK + c) * H_SZ + h];
  const uint_t* p = av + ((size_t)b * T_SZ + c * CHUNK) * H_SZ + h;
  float* o = out + ((size_t)b * T_SZ + c * CHUNK) * H_SZ + h;

  uint_t buf[CHUNK];
#pragma unroll
  for (int s = 0; s < CHUNK; ++s) buf[s] = p[(size_t)s * H_SZ];

#pragma unroll
  for (int s = 0; s < CHUNK; ++s) {
    float a = unpack_lo(buf[s]);
    float v = unpack_hi(buf[s]);
    hc = fmaf(a, hc, v);
    o[(size_t)s * H_SZ] = hc;
  }
}

// Fallback: fully-sequential scan (only if ws too small for summaries).
__global__ __launch_bounds__(64) void scan_seq(const float* __restrict__ h0,
                                               const uint_t* av, float* out) {
  const int b = blockIdx.x >> 2;
  const int hg = blockIdx.x & 3;
  const int h = hg * 64 + threadIdx.x;

  float v0 = h0[b * H_SZ + h];
  float hc = (v0 >= 0.0f) ? (v0 + 0.5f) : sigmoidf_(v0);

  const uint_t* p = av + (size_t)b * T_SZ * H_SZ + h;
  float* o = out + (size_t)b * T_SZ * H_SZ + h;

  uint_t buf[32];
#pragma unroll
  for (int d = 0; d < 32; ++d) buf[d] = p[(size_t)d * H_SZ];

  for (int t0 = 0; t0 < T_SZ; t0 += 32) {
#pragma unroll
    for (int d = 0; d < 32; ++d) {
      int t = t0 + d;
      uint_t pk = buf[d];
      int tn = t + 32;
      if (tn < T_SZ) buf[d] = p[(size_t)tn * H_SZ];
      hc = fmaf(unpack_lo(pk), hc, unpack_hi(pk));
      o[(size_t)t * H_SZ] = hc;
    }
  }
}

extern "C" void kernel_launch(void* const* d_in, const int* in_sizes, int n_in,
                              void* d_out, int out_size, void* d_ws, size_t ws_size,
                              hipStream_t stream) {
  const float* x  = (const float*)d_in[0];
  const float* h0 = (const float*)d_in[1];
  const float* Wz = (const float*)d_in[2];
  const float* bz = (const float*)d_in[3];
  const float* Wh = (const float*)d_in[4];
  const float* bh = (const float*)d_in[5];
  float* out = (float*)d_out;

  // ws layout: [wsB 256K][cAV 4M][hb 2M][pad to 8M][av 134M if it fits]
  const size_t wsBBytes = 262144;
  const size_t cavBytes = (size_t)B_SZ * NCHUNK * H_SZ * 8;   // 4 MiB
  const size_t hbBytes  = (size_t)B_SZ * NCHUNK * H_SZ * 4;   // 2 MiB
  const size_t avOff    = 8388608;
  const size_t avBytes  = (size_t)M_SZ * H_SZ * 4;            // 134 MiB

  ushort_t* wsB = (ushort_t*)d_ws;
  float2* cAV = (float2*)((char*)d_ws + wsBBytes);
  float* hb   = (float*)((char*)d_ws + wsBBytes + cavBytes);

  const bool haveSummaries = ws_size >= wsBBytes + cavBytes + hbBytes;
  uint_t* av;
  if (ws_size >= avOff + avBytes) {
    av = (uint_t*)((char*)d_ws + avOff);
  } else {
    av = (uint_t*)d_out;  // in-place: scan reads av[t] before writing h[t]
  }

  prep_w<<<64, 256, 0, stream>>>(Wz, Wh, wsB);
  gemm_av<<<M_SZ / 64, 512, 0, stream>>>(x, wsB, bz, bh, av);
  if (haveSummaries) {
    chunk_reduce<<<B_SZ * NCHUNK, 256, 0, stream>>>(av, cAV);
    chunk_carry<<<B_SZ, 256, 0, stream>>>(h0, cAV, hb);
    chunk_scan_out<<<B_SZ * NCHUNK, 256, 0, stream>>>(av, hb, out);
  } else {
    scan_seq<<<B_SZ * 4, 64, 0, stream>>>(h0, av, out);
  }
}

// Round 9
// 163.425 us; speedup vs baseline: 1.3553x; 1.2005x over previous
//
#include <hip/hip_runtime.h>
#include <hip/hip_fp16.h>

typedef __attribute__((ext_vector_type(8))) short short8;
typedef __attribute__((ext_vector_type(4))) float f32x4;
typedef unsigned short ushort_t;
typedef unsigned int uint_t;

#define B_SZ 32
#define T_SZ 4096
#define D_IN 256
#define H_SZ 256
#define M_SZ (B_SZ * T_SZ)  // 131072
#define CHUNK 64
#define NCHUNK (T_SZ / CHUNK)  // 64

__device__ __forceinline__ ushort_t f2bf(float f) {
  unsigned int u = __float_as_uint(f);
  unsigned int r = (u + 0x7FFFu + ((u >> 16) & 1u)) >> 16;
  return (ushort_t)r;
}

__device__ __forceinline__ float sigmoidf_(float xv) {
  float e = __expf(-fabsf(xv));
  float s = 1.0f / (1.0f + e);
  return xv >= 0.0f ? s : 1.0f - s;
}

__device__ __forceinline__ float unpack_lo(uint_t pk) {
  return __half2float(__ushort_as_half((ushort_t)(pk & 0xFFFFu)));
}
__device__ __forceinline__ float unpack_hi(uint_t pk) {
  return __half2float(__ushort_as_half((ushort_t)(pk >> 16)));
}

// ---------------------------------------------------------------------------
// Kernel 1 (round-3 verbatim): pack W'' (Wz,Wh interleaved by 16-col groups)
// into bf16 in the GEMM's per-kstep LDS image, GRANULE-MAJOR: granule index
// within a kstep = c*512 + n (c = 16B k-chunk 0..3, n = interleaved col).
// W''[n] -> gate = (n>>4)&1 (0=Wz,1=Wh), h = (n>>5)*16 + (n&15).
// ---------------------------------------------------------------------------
__global__ void prep_w(const float* __restrict__ Wz, const float* __restrict__ Wh,
                       ushort_t* __restrict__ wsB) {
  int g = blockIdx.x * 256 + threadIdx.x;  // 16384 granules total
  if (g >= 8 * 2048) return;
  int ks = g >> 11;
  int r = g & 2047;
  int c = r >> 9;        // 0..3
  int n = r & 511;       // 0..511
  int h = (n >> 5) * 16 + (n & 15);
  const float* W = ((n >> 4) & 1) ? Wh : Wz;
  const float* src = W + (size_t)h * D_IN + ks * 32 + c * 8;
  ushort_t* dst = wsB + (size_t)g * 8;
#pragma unroll
  for (int j = 0; j < 8; ++j) dst[j] = f2bf(src[j]);
}

// ---------------------------------------------------------------------------
// Kernel 2: round-3 GEMM byte-identical through the K-loop and gate math;
// ONE addition: the epilogue also composes this block's 64-step affine
// (A = prod a, V) per h in-register (butterfly shfl over rgrp in time order,
// then ascending rt), writing cAV directly -> chunk_reduce kernel deleted.
// Block = exactly one (b, chunk): chunkIdx == blockIdx.x.
// acc[rt][ct][j] = C[m0 + rt*16 + rgrp*4 + j][wid*64 + ct*16 + col16];
// t_local = rt*16 + rgrp*4 + j (j ascending = time ascending).
// ---------------------------------------------------------------------------
__global__ __launch_bounds__(512, 4) void gemm_av(
    const float* __restrict__ x, const ushort_t* __restrict__ wsB,
    const float* __restrict__ bz, const float* __restrict__ bh,
    uint_t* __restrict__ av, float2* cAV) {
  __shared__ __align__(16) unsigned char lds[73728];
  ushort_t* As = (ushort_t*)lds;                  // 2 x 4096 B  (2048 el/buf)
  ushort_t* Bs = (ushort_t*)(lds + 8192);         // 2 x 32768 B (16384 el/buf)

  const int tid = threadIdx.x;
  const int lane = tid & 63;
  const int wid = tid >> 6;         // 0..7 = N-group
  const int m0 = blockIdx.x * 64;

  // A-stage mapping (threads 0..255): granule G = g*64 + row, g = 16B k-chunk
  const int a_row = tid & 63;
  const int a_g = tid >> 6;         // valid for tid<256
  const float* asrc = x + (size_t)(m0 + a_row) * D_IN + a_g * 8;

  f32x4 acc[4][4];
#pragma unroll
  for (int rt = 0; rt < 4; ++rt)
#pragma unroll
    for (int ct = 0; ct < 4; ++ct) {
      f32x4 z4 = {0.f, 0.f, 0.f, 0.f};
      acc[rt][ct] = z4;
    }

  // ---- prologue: stage kstep 0 into buffer 0 ----
  {
    const ushort_t* bsrc = wsB + (size_t)wid * 2048 + lane * 8;
    ushort_t* bdst = Bs + wid * 2048;
#pragma unroll
    for (int cc = 0; cc < 4; ++cc) {
      __builtin_amdgcn_global_load_lds(
          (const __attribute__((address_space(1))) void*)(bsrc + cc * 512),
          (__attribute__((address_space(3))) void*)(bdst + cc * 512), 16, 0, 0);
    }
    if (tid < 256) {
      float4 f0 = *(const float4*)(asrc);
      float4 f1 = *(const float4*)(asrc + 4);
      union { ushort_t e[8]; short8 s; } cv;
      cv.e[0] = f2bf(f0.x); cv.e[1] = f2bf(f0.y);
      cv.e[2] = f2bf(f0.z); cv.e[3] = f2bf(f0.w);
      cv.e[4] = f2bf(f1.x); cv.e[5] = f2bf(f1.y);
      cv.e[6] = f2bf(f1.z); cv.e[7] = f2bf(f1.w);
      *(short8*)(As + tid * 8) = cv.s;
    }
  }
  __syncthreads();

#pragma unroll
  for (int ks = 0; ks < 8; ++ks) {
    const int cur = ks & 1;
    // 1. LDS -> register fragments (granule-major: granule = c*NROWS + idx)
    short8 afr[4], bfr[4];
    {
      const int c = lane >> 4;
      const int r16 = lane & 15;
#pragma unroll
      for (int rt = 0; rt < 4; ++rt) {
        int row = rt * 16 + r16;
        afr[rt] = *(const short8*)(As + cur * 2048 + (c * 64 + row) * 8);
      }
#pragma unroll
      for (int ct = 0; ct < 4; ++ct) {
        int n = wid * 64 + ct * 16 + r16;
        bfr[ct] = *(const short8*)(Bs + cur * 16384 + (c * 512 + n) * 8);
      }
    }
    // 2. issue next-tile staging (latency hides under MFMAs)
    float4 nf0, nf1;
    if (ks < 7) {
      const ushort_t* bsrc = wsB + (size_t)(ks + 1) * 16384 + wid * 2048 + lane * 8;
      ushort_t* bdst = Bs + (cur ^ 1) * 16384 + wid * 2048;
#pragma unroll
      for (int cc = 0; cc < 4; ++cc) {
        __builtin_amdgcn_global_load_lds(
            (const __attribute__((address_space(1))) void*)(bsrc + cc * 512),
            (__attribute__((address_space(3))) void*)(bdst + cc * 512), 16, 0, 0);
      }
      if (tid < 256) {
        nf0 = *(const float4*)(asrc + (ks + 1) * 32);
        nf1 = *(const float4*)(asrc + (ks + 1) * 32 + 4);
      }
    }
    // 3. MFMAs
#pragma unroll
    for (int rt = 0; rt < 4; ++rt)
#pragma unroll
      for (int ct = 0; ct < 4; ++ct)
        acc[rt][ct] = __builtin_amdgcn_mfma_f32_16x16x32_bf16(
            afr[rt], bfr[ct], acc[rt][ct], 0, 0, 0);
    // 4. A write-late (reg->LDS after compute)
    if (ks < 7 && tid < 256) {
      union { ushort_t e[8]; short8 s; } cv;
      cv.e[0] = f2bf(nf0.x); cv.e[1] = f2bf(nf0.y);
      cv.e[2] = f2bf(nf0.z); cv.e[3] = f2bf(nf0.w);
      cv.e[4] = f2bf(nf1.x); cv.e[5] = f2bf(nf1.y);
      cv.e[6] = f2bf(nf1.z); cv.e[7] = f2bf(nf1.w);
      *(short8*)(As + (cur ^ 1) * 2048 + tid * 8) = cv.s;
    }
    __syncthreads();
  }

  // ---- epilogue: r3 gate math + av store, PLUS fused chunk-affine reduce ----
  const int col16 = lane & 15;
  const int rgrp = lane >> 4;
#pragma unroll
  for (int i = 0; i < 2; ++i) {
    int hh = (wid * 2 + i) * 16 + col16;
    float bzv = bz[hh];
    float bhv = bh[hh];
    float CA = 1.0f, CV = 0.0f;   // running compose over rt windows
#pragma unroll
    for (int rt = 0; rt < 4; ++rt) {
      float A4 = 1.0f, V4 = 0.0f; // compose of this thread's 4 rows (ascending j)
#pragma unroll
      for (int j = 0; j < 4; ++j) {
        int row = m0 + rt * 16 + rgrp * 4 + j;
        float kv = acc[rt][2 * i][j] + bzv;
        float pv = acc[rt][2 * i + 1][j] + bhv;
        float a = sigmoidf_(-kv);       // 1 - sigmoid(k)
        float z = 1.0f - a;             // sigmoid(k)
        float gg = (pv >= 0.0f) ? (pv + 0.5f) : sigmoidf_(pv);
        float vv = z * gg;
        uint_t pk = (uint_t)__half_as_ushort(__float2half_rn(a)) |
                    ((uint_t)__half_as_ushort(__float2half_rn(vv)) << 16);
        av[(size_t)row * H_SZ + hh] = pk;
        V4 = fmaf(a, V4, vv);
        A4 *= a;
      }
      // butterfly compose across rgrp (time order: rgrp0 rows 0-3, ... rgrp3 12-15)
      float Ap = __shfl_xor(A4, 16);
      float Vp = __shfl_xor(V4, 16);
      float A8 = A4 * Ap;
      float V8 = (lane & 16) ? fmaf(A4, Vp, V4) : fmaf(Ap, V4, Vp);
      float Ap2 = __shfl_xor(A8, 32);
      float Vp2 = __shfl_xor(V8, 32);
      float A16 = A8 * Ap2;
      float V16 = (lane & 32) ? fmaf(A8, Vp2, V8) : fmaf(Ap2, V8, Vp2);
      // rt windows ascend in time
      CV = fmaf(A16, CV, V16);
      CA = CA * A16;
    }
    if (cAV != nullptr && lane < 16) {
      float2 r; r.x = CA; r.y = CV;
      cAV[(size_t)blockIdx.x * H_SZ + hh] = r;  // chunkIdx == blockIdx.x
    }
  }
}

// ---------------------------------------------------------------------------
// Phase 2: per (b,h): sequentially compose chunk summaries from g(h0),
// writing the INCOMING h for each chunk. 32 blocks x 256 thr.
// ---------------------------------------------------------------------------
__global__ __launch_bounds__(256) void chunk_carry(
    const float* __restrict__ h0, const float2* __restrict__ cAV,
    float* __restrict__ hb) {
  const int b = blockIdx.x;
  const int h = threadIdx.x;
  float v0 = h0[b * H_SZ + h];
  float hc = (v0 >= 0.0f) ? (v0 + 0.5f) : sigmoidf_(v0);

  const float2* p = cAV + (size_t)b * NCHUNK * H_SZ + h;
  float* o = hb + (size_t)b * NCHUNK * H_SZ + h;

  float2 buf[NCHUNK];
#pragma unroll
  for (int c = 0; c < NCHUNK; ++c) buf[c] = p[(size_t)c * H_SZ];

#pragma unroll
  for (int c = 0; c < NCHUNK; ++c) {
    o[(size_t)c * H_SZ] = hc;
    hc = fmaf(buf[c].x, hc, buf[c].y);
  }
}

// ---------------------------------------------------------------------------
// Phase 3: per (b, chunk): start from carry, re-scan av, write fp32 out.
// av may alias out (in-place fallback): per-thread loads strictly precede
// stores to the same addresses; no __restrict__ on av/out.
// ---------------------------------------------------------------------------
__global__ __launch_bounds__(256) void chunk_scan_out(
    const uint_t* av, const float* __restrict__ hb, float* out) {
  const int b = blockIdx.x >> 6;
  const int c = blockIdx.x & 63;
  const int h = threadIdx.x;

  float hc = hb[((size_t)b * NCHUNK + c) * H_SZ + h];
  const uint_t* p = av + ((size_t)b * T_SZ + c * CHUNK) * H_SZ + h;
  float* o = out + ((size_t)b * T_SZ + c * CHUNK) * H_SZ + h;

  uint_t buf[CHUNK];
#pragma unroll
  for (int s = 0; s < CHUNK; ++s) buf[s] = p[(size_t)s * H_SZ];

#pragma unroll
  for (int s = 0; s < CHUNK; ++s) {
    float a = unpack_lo(buf[s]);
    float v = unpack_hi(buf[s]);
    hc = fmaf(a, hc, v);
    o[(size_t)s * H_SZ] = hc;
  }
}

// Fallback: fully-sequential scan (only if ws too small for summaries).
__global__ __launch_bounds__(64) void scan_seq(const float* __restrict__ h0,
                                               const uint_t* av, float* out) {
  const int b = blockIdx.x >> 2;
  const int hg = blockIdx.x & 3;
  const int h = hg * 64 + threadIdx.x;

  float v0 = h0[b * H_SZ + h];
  float hc = (v0 >= 0.0f) ? (v0 + 0.5f) : sigmoidf_(v0);

  const uint_t* p = av + (size_t)b * T_SZ * H_SZ + h;
  float* o = out + (size_t)b * T_SZ * H_SZ + h;

  uint_t buf[32];
#pragma unroll
  for (int d = 0; d < 32; ++d) buf[d] = p[(size_t)d * H_SZ];

  for (int t0 = 0; t0 < T_SZ; t0 += 32) {
#pragma unroll
    for (int d = 0; d < 32; ++d) {
      int t = t0 + d;
      uint_t pk = buf[d];
      int tn = t + 32;
      if (tn < T_SZ) buf[d] = p[(size_t)tn * H_SZ];
      hc = fmaf(unpack_lo(pk), hc, unpack_hi(pk));
      o[(size_t)t * H_SZ] = hc;
    }
  }
}

extern "C" void kernel_launch(void* const* d_in, const int* in_sizes, int n_in,
                              void* d_out, int out_size, void* d_ws, size_t ws_size,
                              hipStream_t stream) {
  const float* x  = (const float*)d_in[0];
  const float* h0 = (const float*)d_in[1];
  const float* Wz = (const float*)d_in[2];
  const float* bz = (const float*)d_in[3];
  const float* Wh = (const float*)d_in[4];
  const float* bh = (const float*)d_in[5];
  float* out = (float*)d_out;

  // ws layout: [wsB 256K][cAV 4M][hb 2M][pad to 8M][av 134M if it fits]
  const size_t wsBBytes = 262144;
  const size_t cavBytes = (size_t)B_SZ * NCHUNK * H_SZ * 8;   // 4 MiB
  const size_t hbBytes  = (size_t)B_SZ * NCHUNK * H_SZ * 4;   // 2 MiB
  const size_t avOff    = 8388608;
  const size_t avBytes  = (size_t)M_SZ * H_SZ * 4;            // 134 MiB

  ushort_t* wsB = (ushort_t*)d_ws;
  float2* cAV = (float2*)((char*)d_ws + wsBBytes);
  float* hb   = (float*)((char*)d_ws + wsBBytes + cavBytes);

  const bool haveSummaries = ws_size >= wsBBytes + cavBytes + hbBytes;
  uint_t* av;
  if (ws_size >= avOff + avBytes) {
    av = (uint_t*)((char*)d_ws + avOff);
  } else {
    av = (uint_t*)d_out;  // in-place: scan reads av[t] before writing h[t]
  }

  prep_w<<<64, 256, 0, stream>>>(Wz, Wh, wsB);
  gemm_av<<<M_SZ / 64, 512, 0, stream>>>(x, wsB, bz, bh, av,
                                         haveSummaries ? cAV : (float2*)nullptr);
  if (haveSummaries) {
    chunk_carry<<<B_SZ, 256, 0, stream>>>(h0, cAV, hb);
    chunk_scan_out<<<B_SZ * NCHUNK, 256, 0, stream>>>(av, hb, out);
  } else {
    scan_seq<<<B_SZ * 4, 64, 0, stream>>>(h0, av, out);
  }
}